// Round 3
// baseline (158.224 us; speedup 1.0000x reference)
//
#include <hip/hip_runtime.h>
#include <stdint.h>

typedef unsigned short u16;
typedef __attribute__((ext_vector_type(8)))  short short8;
typedef __attribute__((ext_vector_type(16))) float f32x16;
typedef __attribute__((ext_vector_type(4)))  float f32x4;

#define RROW 128          // LDS bytes per row (64 ch * 2B)
#define RREG 9856         // per (sample,chunk) region: 77 rows * 128
#define SSTR 39424        // per-sample stride: 4 regions
#define LDSB (4*SSTR)     // 157696
#define PACK_BYTES (1920ull*1024ull)
#define ZMASK 0x07AB01AA80EAE0FAull

// per-pixel (0..63) LDS write targets (padded sp indices), 255 = none
__device__ const uint8_t WSP[64][3] = {
  {11,95,255},{12,255,255},{13,97,255},{14,255,255},{255,255,255},{16,255,255},{17,255,255},{18,255,255},
  {21,69,255},{22,255,255},{23,255,255},{24,255,255},{25,61,255},{255,255,255},{27,255,255},{28,255,255},
  {31,79,255},{32,255,255},{33,255,255},{34,255,255},{35,255,255},{36,255,255},{255,255,255},{38,255,255},
  {41,89,255},{42,255,255},{43,255,255},{44,255,255},{45,255,255},{46,255,255},{47,83,255},{255,255,255},
  {51,15,99},{52,255,255},{53,255,255},{54,255,255},{55,255,255},{56,255,255},{57,255,255},{58,255,255},
  {255,255,255},{62,26,255},{63,255,255},{64,255,255},{65,255,255},{66,255,255},{67,255,255},{68,20,255},
  {71,255,255},{72,255,255},{73,37,255},{74,255,255},{75,255,255},{76,255,255},{77,255,255},{78,255,255},
  {81,255,255},{82,255,255},{255,255,255},{84,0,48},{85,1,255},{86,2,255},{87,3,255},{88,40,255}
};

// padded sp -> compact LDS row slot; 76 = shared zero row
__device__ const uint8_t SLOT100[100] = {
   0, 1, 2, 3,76,76,76,76,76,76,
  76, 4, 5, 6, 7, 8, 9,10,11,76,
  12,13,14,15,16,17,18,19,20,76,
  76,21,22,23,24,25,26,27,28,76,
  29,30,31,32,33,34,35,36,37,76,
  76,38,39,40,41,42,43,44,45,76,
  76,46,47,48,49,50,51,52,53,54,
  76,55,56,57,58,59,60,61,62,63,
  76,64,65,66,67,68,69,70,71,72,
  76,76,76,76,76,73,76,74,76,75
};

// tap offsets per direction: 0=up, 1=left, 2=right
__device__ const int8_t TAPR[3][5] = {{0,0,1,2,2},{1,2,2,2,3},{1,2,2,2,3}};
__device__ const int8_t TAPC[3][5] = {{0,1,1,1,2},{1,0,1,2,1},{1,1,2,3,3}};

// padded sp -> source pixel (0..63) or -1 (zero); includes the 18 fixup copies
__device__ const int8_t MAP100[100] = {
  59,60,61,62,-1,-1,-1,-1,-1,-1,
  -1, 0, 1, 2, 3,32, 5, 6, 7,-1,
  47, 8, 9,10,11,12,41,14,15,-1,
  -1,16,17,18,19,20,21,50,23,-1,
  63,24,25,26,27,28,29,30,59,-1,
  -1,32,33,34,35,36,37,38,39,-1,
  -1,12,41,42,43,44,45,46,47, 8,
  -1,48,49,50,51,52,53,54,55,16,
  -1,56,57,30,59,60,61,62,63,24,
  -1,-1,-1,-1,-1, 0,-1, 2,-1,32
};

// 3-bit granule hash: per tap, covers each of 8 bank groups exactly 2x
__device__ __forceinline__ int h3sp(int sp) {
  int r = sp / 10;
  int c = sp - r * 10;
  return ((r >> 1) + 4 * ((c >> 1) & 1)) & 7;
}

__device__ __forceinline__ u16 f2bf(float f) {
  uint32_t u = __float_as_uint(f);
  return (u16)((u + 0x7FFFu + ((u >> 16) & 1)) >> 16);   // RNE
}

// ---------------- weight pre-pack: exact B-fragment order -------------------
// frag = ((d*5+t)*16+cb)*8+nt ; lane l holds B[k=8*(l>>5)+e][n=l&31]
__global__ __launch_bounds__(256) void kag_prep(const float* __restrict__ wU,
                                                const float* __restrict__ wL,
                                                const float* __restrict__ wR,
                                                u16* __restrict__ pack) {
  int tid  = blockIdx.x * 256 + threadIdx.x;     // 0..122879
  int l    = tid & 63;
  int frag = tid >> 6;                           // 0..1919
  int d    = frag / 640;
  int rem  = frag - d * 640;
  int t    = rem >> 7;
  int rem2 = rem & 127;
  int cb   = rem2 >> 3;
  int nt   = rem2 & 7;
  const float* w = (d == 0) ? wU : ((d == 1) ? wL : wR);
  int tr = TAPR[d][t], tc = TAPC[d][t];
  int o  = nt * 32 + (l & 31);
  int c0 = cb * 16 + ((l >> 5) << 3);
  const float* wp = w + (size_t)o * 4096 + (size_t)c0 * 16 + tr * 4 + tc;
  union { u16 u[8]; short8 v; } cv;
#pragma unroll
  for (int e = 0; e < 8; ++e) cv.u[e] = f2bf(wp[e * 16]);
  *(short8*)(pack + (size_t)frag * 512 + l * 8) = cv.v;
}

// ------- main kernel: 4 samples/block, chunked staging overlapped with K ----
__global__ __launch_bounds__(768, 3) void kag_main(const float* __restrict__ x,
                                                   const u16* __restrict__ pack,
                                                   const float* __restrict__ bU,
                                                   const float* __restrict__ bL,
                                                   const float* __restrict__ bR,
                                                   float* __restrict__ out) {
  extern __shared__ __align__(16) char lds[];
  const int tid = threadIdx.x;
  const int l   = tid & 63;
  const int w   = tid >> 6;          // 0..11
  const int b0  = blockIdx.x * 4;

  // zero rows: 16 regions * slot 76 * 8 granules
  if (tid < 128) {
    int re = tid >> 3;
    int g  = tid & 7;
    *(short8*)(lds + re * RREG + 76 * RROW + g * 16) = (short8)(short)0;
  }

  // per-lane staging write targets
  int wrow[3], whh[3];
#pragma unroll
  for (int k2 = 0; k2 < 3; ++k2) {
    int spv = WSP[l][k2];
    if (spv < 255) { wrow[k2] = SLOT100[spv] * RROW; whh[k2] = h3sp(spv); }
    else           { wrow[k2] = 0;                   whh[k2] = -1; }
  }

  // ---- prologue: stage chunk 0 directly ----
#pragma unroll
  for (int jb = 0; jb < 3; ++jb) {
    int job = w + jb * 12;
    if (job < 32) {
      int sj = job >> 3, gj = job & 7;
      const float* xs = x + (size_t)(b0 + sj) * 16384 + (size_t)(gj * 8) * 64 + l;
      union { u16 u[8]; short8 v; } cv;
#pragma unroll
      for (int e = 0; e < 8; ++e) cv.u[e] = f2bf(xs[e * 64]);
#pragma unroll
      for (int k2 = 0; k2 < 3; ++k2)
        if (whh[k2] >= 0)
          *(short8*)(lds + sj * SSTR + wrow[k2] + ((gj ^ whh[k2]) << 4)) = cv.v;
    }
  }
  __syncthreads();

  // ---- MFMA setup ----
  const int d   = w >> 2;
  const int nt0 = w & 3;
  const int m   = l & 31;
  const int sA  = m >> 4;
  const int pos = m & 15;
  const int i   = pos >> 2, j = pos & 3;
  const int lh  = l >> 5;

  int rowoff[5], h3t[5];
#pragma unroll
  for (int t = 0; t < 5; ++t) {
    int tr = TAPR[d][t], tc = TAPC[d][t];
    int sp = (2 * i + tr) * 10 + (2 * j + tc);
    rowoff[t] = SLOT100[sp] * RROW;
    h3t[t]    = h3sp(sp);
  }
  const int sb0 = sA * SSTR;            // sample sA
  const int sb1 = sb0 + 2 * SSTR;       // sample sA+2

  f32x16 acc[2][2];
#pragma unroll
  for (int p = 0; p < 2; ++p)
#pragma unroll
    for (int h = 0; h < 2; ++h)
#pragma unroll
      for (int r2 = 0; r2 < 16; ++r2) acc[p][h][r2] = 0.f;

  const char* pkc = (const char*)pack + (size_t)((d * 640 + nt0) * 1024) + l * 16;

  short8 wq[3][2];
  short8 aq[2][2];

  // prime B stages 0,1 ; A stage 0 (t=0, cb=0 -> granule lh^h3t[0], q=0)
#pragma unroll
  for (int s = 0; s < 2; ++s) {
    const int cb = s / 5, t = s % 5;
    const size_t bo = (size_t)(t * 16 + cb) * 8192;
    wq[s][0] = *(const short8*)(pkc + bo);
    wq[s][1] = *(const short8*)(pkc + bo + 4096);
  }
  {
    const int off = rowoff[0] + (((lh) ^ h3t[0]) << 4);
    aq[0][0] = *(const short8*)(lds + sb0 + off);
    aq[0][1] = *(const short8*)(lds + sb1 + off);
  }

  float xr[3][8];

#pragma unroll
  for (int q = 0; q < 4; ++q) {
    // issue next chunk's x loads (registers); converted+written at chunk end
    if (q < 3) {
#pragma unroll
      for (int jb = 0; jb < 3; ++jb) {
        int job = w + jb * 12;
        if (job < 32) {
          int sj = job >> 3, gj = job & 7;
          const float* xs = x + (size_t)(b0 + sj) * 16384 +
                            (size_t)((q + 1) * 64 + gj * 8) * 64 + l;
#pragma unroll
          for (int e = 0; e < 8; ++e) xr[jb][e] = xs[e * 64];
        }
      }
    }
#pragma unroll
    for (int s2 = 0; s2 < 20; ++s2) {
      const int s = q * 20 + s2;
      if (s + 2 < 80) {                       // B prefetch, depth 2
        const int s3 = s + 2, cb3 = s3 / 5, t3 = s3 - cb3 * 5;
        const size_t bo = (size_t)(t3 * 16 + cb3) * 8192;
        wq[s3 % 3][0] = *(const short8*)(pkc + bo);
        wq[s3 % 3][1] = *(const short8*)(pkc + bo + 4096);
      }
      if (s2 < 19) {                          // A prefetch, depth 1 (chunk-local)
        const int s1 = s + 1, cb1 = s1 / 5, t1 = s1 - cb1 * 5;
        const int g1 = ((cb1 & 3) * 2 + lh) ^ h3t[t1];
        const int off = q * RREG + rowoff[t1] + (g1 << 4);
        aq[s1 & 1][0] = *(const short8*)(lds + sb0 + off);
        aq[s1 & 1][1] = *(const short8*)(lds + sb1 + off);
      }
      acc[0][0] = __builtin_amdgcn_mfma_f32_32x32x16_bf16(aq[s & 1][0], wq[s % 3][0], acc[0][0], 0, 0, 0);
      acc[0][1] = __builtin_amdgcn_mfma_f32_32x32x16_bf16(aq[s & 1][0], wq[s % 3][1], acc[0][1], 0, 0, 0);
      acc[1][0] = __builtin_amdgcn_mfma_f32_32x32x16_bf16(aq[s & 1][1], wq[s % 3][0], acc[1][0], 0, 0, 0);
      acc[1][1] = __builtin_amdgcn_mfma_f32_32x32x16_bf16(aq[s & 1][1], wq[s % 3][1], acc[1][1], 0, 0, 0);
    }
    if (q < 3) {
      // convert + scatter next chunk into LDS, then barrier
#pragma unroll
      for (int jb = 0; jb < 3; ++jb) {
        int job = w + jb * 12;
        if (job < 32) {
          int sj = job >> 3, gj = job & 7;
          union { u16 u[8]; short8 v; } cv;
#pragma unroll
          for (int e = 0; e < 8; ++e) cv.u[e] = f2bf(xr[jb][e]);
#pragma unroll
          for (int k2 = 0; k2 < 3; ++k2)
            if (whh[k2] >= 0)
              *(short8*)(lds + sj * SSTR + (q + 1) * RREG + wrow[k2] +
                         ((gj ^ whh[k2]) << 4)) = cv.v;
        }
      }
      __syncthreads();
      // prime A for next chunk (t=0, cbL=0)
      const int off = (q + 1) * RREG + rowoff[0] + ((lh ^ h3t[0]) << 4);
      aq[0][0] = *(const short8*)(lds + sb0 + off);
      aq[0][1] = *(const short8*)(lds + sb1 + off);
    }
  }
  __syncthreads();

  // ---- epilogue: LDS out-tile (swizzled), bias + zero-mask ----
  const float* bp = (d == 0) ? bU : ((d == 1) ? bL : bR);
  const int ol = l & 31;
  const int o0 = nt0 * 32 + ol;
  const int o1 = o0 + 128;
  const float bias0 = bp[o0];
  const float bias1 = bp[o1];
  const int lh4 = lh * 4;
  float* ldsf = (float*)lds;

#pragma unroll
  for (int s4 = 0; s4 < 4; ++s4) {
    const int p  = s4 >> 1;
    const int hs = s4 & 1;
#pragma unroll
    for (int r2 = 0; r2 < 16; ++r2) {
      int row = (r2 & 3) + 8 * (r2 >> 2) + lh4;
      if ((row >> 4) == hs) {
        int p2 = row & 15;
        int i2 = p2 >> 2, j2 = p2 & 3;
        int outp = 16 * i2 + 2 * j2 + ((d > 0) ? 8 : 0) + (d >> 1);
        ldsf[o0 * 64 + (outp ^ ((o0 & 15) << 2))] = acc[p][0][r2] + bias0;
        ldsf[o1 * 64 + (outp ^ ((o1 & 15) << 2))] = acc[p][1][r2] + bias1;
      }
    }
    __syncthreads();
    for (int cc = tid; cc < 4096; cc += 768) {
      int o  = cc >> 4, pb = cc & 15;
      f32x4 v = *(f32x4*)(ldsf + o * 64 + ((pb ^ (o & 15)) << 2));
#pragma unroll
      for (int kk = 0; kk < 4; ++kk)
        if ((ZMASK >> (pb * 4 + kk)) & 1ull) v[kk] = 0.f;
      *(f32x4*)(out + (((size_t)(b0 + s4) * 256 + o) << 6) + pb * 4) = v;
    }
    __syncthreads();
  }
}

// ---------------- slow fp32 fallback (only if ws too small) -----------------
__global__ __launch_bounds__(256) void kag_fallback(const float* __restrict__ x,
    const float* __restrict__ wU, const float* __restrict__ bU,
    const float* __restrict__ wL, const float* __restrict__ bL,
    const float* __restrict__ wR, const float* __restrict__ bR,
    float* __restrict__ out) {
  long long tid = (long long)blockIdx.x * 256 + threadIdx.x;
  if (tid >= (long long)2048 * 256 * 48) return;
  int pd = (int)(tid % 48);
  long long rem = tid / 48;
  int o = (int)(rem % 256);
  int b = (int)(rem / 256);
  int d = pd >> 4, pos = pd & 15;
  int i = pos >> 2, j = pos & 3;
  int outp = 16 * i + 2 * j + ((d > 0) ? 8 : 0) + (d >> 1);
  if ((ZMASK >> outp) & 1ull) return;
  const float* ws = (d == 0) ? wU : ((d == 1) ? wL : wR);
  const float* bs = (d == 0) ? bU : ((d == 1) ? bL : bR);
  float acc = bs[o];
  int spv[5], wofs[5];
#pragma unroll
  for (int t = 0; t < 5; ++t) {
    int tr = TAPR[d][t], tc = TAPC[d][t];
    spv[t]  = (2 * i + tr) * 10 + (2 * j + tc);
    wofs[t] = tr * 4 + tc;
  }
  for (int c = 0; c < 256; ++c) {
    const float* xc = x + ((size_t)b * 256 + c) * 64;
    const float* wc = ws + (size_t)o * 4096 + (size_t)c * 16;
#pragma unroll
    for (int t = 0; t < 5; ++t) {
      int px = MAP100[spv[t]];
      if (px >= 0) acc += xc[px] * wc[wofs[t]];
    }
  }
  out[((size_t)b * 256 + o) * 64 + outp] = acc;
}

extern "C" void kernel_launch(void* const* d_in, const int* in_sizes, int n_in,
                              void* d_out, int out_size, void* d_ws, size_t ws_size,
                              hipStream_t stream) {
  const float* x  = (const float*)d_in[0];
  const float* wU = (const float*)d_in[1];
  const float* bU = (const float*)d_in[2];
  const float* wL = (const float*)d_in[3];
  const float* bL = (const float*)d_in[4];
  const float* wR = (const float*)d_in[5];
  const float* bR = (const float*)d_in[6];
  float* out = (float*)d_out;

  if (ws_size >= PACK_BYTES) {
    u16* pack = (u16*)d_ws;
    kag_prep<<<480, 256, 0, stream>>>(wU, wL, wR, pack);
    hipFuncSetAttribute(reinterpret_cast<const void*>(kag_main),
                        hipFuncAttributeMaxDynamicSharedMemorySize, LDSB);
    kag_main<<<512, 768, LDSB, stream>>>(x, pack, bU, bL, bR, out);
  } else {
    hipMemsetAsync(d_out, 0, (size_t)out_size * 4, stream);
    kag_fallback<<<98304, 256, 0, stream>>>(x, wU, bU, wL, bL, wR, bR, out);
  }
}

// Round 4
// 114.166 us; speedup vs baseline: 1.3859x; 1.3859x over previous
//
#include <hip/hip_runtime.h>
#include <stdint.h>

typedef unsigned short u16;
typedef __attribute__((ext_vector_type(8)))  short short8;
typedef __attribute__((ext_vector_type(16))) float f32x16;
typedef __attribute__((ext_vector_type(4)))  float f32x4;

#define HSTR 19712        // per (sample,half) region: 77 rows * 256B
#define SSTR (2*HSTR)     // per-sample stride
#define LDSB (4*SSTR)     // 157696
#define PACK_BYTES (1920ull*1024ull)
#define ZMASK 0x07AB01AA80EAE0FAull

// per-pixel (0..63) LDS write targets (padded sp indices), 255 = none
__device__ const uint8_t WSP[64][3] = {
  {11,95,255},{12,255,255},{13,97,255},{14,255,255},{255,255,255},{16,255,255},{17,255,255},{18,255,255},
  {21,69,255},{22,255,255},{23,255,255},{24,255,255},{25,61,255},{255,255,255},{27,255,255},{28,255,255},
  {31,79,255},{32,255,255},{33,255,255},{34,255,255},{35,255,255},{36,255,255},{255,255,255},{38,255,255},
  {41,89,255},{42,255,255},{43,255,255},{44,255,255},{45,255,255},{46,255,255},{47,83,255},{255,255,255},
  {51,15,99},{52,255,255},{53,255,255},{54,255,255},{55,255,255},{56,255,255},{57,255,255},{58,255,255},
  {255,255,255},{62,26,255},{63,255,255},{64,255,255},{65,255,255},{66,255,255},{67,255,255},{68,20,255},
  {71,255,255},{72,255,255},{73,37,255},{74,255,255},{75,255,255},{76,255,255},{77,255,255},{78,255,255},
  {81,255,255},{82,255,255},{255,255,255},{84,0,48},{85,1,255},{86,2,255},{87,3,255},{88,40,255}
};

// padded sp -> compact LDS row slot; 76 = shared zero row
__device__ const uint8_t SLOT100[100] = {
   0, 1, 2, 3,76,76,76,76,76,76,
  76, 4, 5, 6, 7, 8, 9,10,11,76,
  12,13,14,15,16,17,18,19,20,76,
  76,21,22,23,24,25,26,27,28,76,
  29,30,31,32,33,34,35,36,37,76,
  76,38,39,40,41,42,43,44,45,76,
  76,46,47,48,49,50,51,52,53,54,
  76,55,56,57,58,59,60,61,62,63,
  76,64,65,66,67,68,69,70,71,72,
  76,76,76,76,76,73,76,74,76,75
};

// tap offsets per direction: 0=up, 1=left, 2=right
__device__ const int8_t TAPR[3][5] = {{0,0,1,2,2},{1,2,2,2,3},{1,2,2,2,3}};
__device__ const int8_t TAPC[3][5] = {{0,1,1,1,2},{1,0,1,2,1},{1,1,2,3,3}};

// padded sp -> source pixel (0..63) or -1 (zero); includes the 18 fixup copies
__device__ const int8_t MAP100[100] = {
  59,60,61,62,-1,-1,-1,-1,-1,-1,
  -1, 0, 1, 2, 3,32, 5, 6, 7,-1,
  47, 8, 9,10,11,12,41,14,15,-1,
  -1,16,17,18,19,20,21,50,23,-1,
  63,24,25,26,27,28,29,30,59,-1,
  -1,32,33,34,35,36,37,38,39,-1,
  -1,12,41,42,43,44,45,46,47, 8,
  -1,48,49,50,51,52,53,54,55,16,
  -1,56,57,30,59,60,61,62,63,24,
  -1,-1,-1,-1,-1, 0,-1, 2,-1,32
};

// 4-bit granule hash: 16 distinct values across any tap's 16 positions
__device__ __forceinline__ int hsp4(int sp) {
  int r = sp / 10;
  int c = sp - r * 10;
  return ((r >> 1) + 4 * (c >> 1)) & 15;
}

__device__ __forceinline__ u16 f2bf(float f) {
  uint32_t u = __float_as_uint(f);
  return (u16)((u + 0x7FFFu + ((u >> 16) & 1)) >> 16);   // RNE
}

// ---------------- weight pre-pack: exact B-fragment order -------------------
__global__ __launch_bounds__(256) void kag_prep(const float* __restrict__ wU,
                                                const float* __restrict__ wL,
                                                const float* __restrict__ wR,
                                                u16* __restrict__ pack) {
  int tid  = blockIdx.x * 256 + threadIdx.x;
  int l    = tid & 63;
  int frag = tid >> 6;                           // 0..1919
  int d    = frag / 640;
  int rem  = frag - d * 640;
  int t    = rem >> 7;
  int rem2 = rem & 127;
  int cb   = rem2 >> 3;
  int nt   = rem2 & 7;
  const float* w = (d == 0) ? wU : ((d == 1) ? wL : wR);
  int tr = TAPR[d][t], tc = TAPC[d][t];
  int o  = nt * 32 + (l & 31);
  int c0 = cb * 16 + ((l >> 5) << 3);
  const float* wp = w + (size_t)o * 4096 + (size_t)c0 * 16 + tr * 4 + tc;
  union { u16 u[8]; short8 v; } cv;
#pragma unroll
  for (int e = 0; e < 8; ++e) cv.u[e] = f2bf(wp[e * 16]);
  *(short8*)(pack + (size_t)frag * 512 + l * 8) = cv.v;
}

// ------- main: 4 samples/block, half-K chunks, hf1 staged under hf0 compute --
__global__ __launch_bounds__(768, 3) void kag_main(const float* __restrict__ x,
                                                   const u16* __restrict__ pack,
                                                   const float* __restrict__ bU,
                                                   const float* __restrict__ bL,
                                                   const float* __restrict__ bR,
                                                   float* __restrict__ out) {
  extern __shared__ __align__(16) char lds[];
  const int tid = threadIdx.x;
  const int l   = tid & 63;
  const int w   = tid >> 6;          // 0..11
  const int b0  = blockIdx.x * 4;

  // zero rows: 4 samples * 2 halves * slot76 * 16 granules
  if (tid < 128) {
    int s  = tid >> 5;
    int hf = (tid >> 4) & 1;
    int g  = tid & 15;
    *(short8*)(lds + s * SSTR + hf * HSTR + 76 * 256 + g * 16) = (short8)(short)0;
  }

  // per-lane staging write targets
  int wrow[3], whh[3];
#pragma unroll
  for (int k2 = 0; k2 < 3; ++k2) {
    int spv = WSP[l][k2];
    if (spv < 255) { wrow[k2] = SLOT100[spv] * 256; whh[k2] = hsp4(spv); }
    else           { wrow[k2] = 0;                  whh[k2] = -1; }
  }

  const float* xw = x + (size_t)b0 * 16384 + l;

  // ---- prologue: stage half 0 (channels 0..127) ----
  for (int rr = 0; rr < 6; ++rr) {
    int job = rr * 12 + w;
    if (job < 64) {
      int sj = job >> 4, g16 = job & 15;
      const float* xs = xw + (size_t)sj * 16384 + g16 * 8 * 64;
      union { u16 u[8]; short8 v; } cv;
#pragma unroll
      for (int e = 0; e < 8; ++e) cv.u[e] = f2bf(xs[e * 64]);
#pragma unroll
      for (int k2 = 0; k2 < 3; ++k2)
        if (whh[k2] >= 0)
          *(short8*)(lds + sj * SSTR + wrow[k2] + ((g16 ^ whh[k2]) << 4)) = cv.v;
    }
  }
  __syncthreads();

  // ---- MFMA setup ----
  const int d   = w >> 2;
  const int nt0 = w & 3;
  const int m   = l & 31;
  const int sA  = m >> 4;
  const int pos = m & 15;
  const int i   = pos >> 2, j = pos & 3;
  const int lh  = l >> 5;

  int P0[5], hh5[5];
#pragma unroll
  for (int t = 0; t < 5; ++t) {
    int tr = TAPR[d][t], tc = TAPC[d][t];
    int sp = (2 * i + tr) * 10 + (2 * j + tc);
    int h4 = hsp4(sp);
    P0[t]  = sA * SSTR + SLOT100[sp] * 256 + ((lh ^ (h4 & 1)) << 4);
    hh5[t] = (h4 >> 1) << 5;
  }

  f32x16 acc[2][2];
#pragma unroll
  for (int p = 0; p < 2; ++p)
#pragma unroll
    for (int h = 0; h < 2; ++h)
#pragma unroll
      for (int r2 = 0; r2 < 16; ++r2) acc[p][h][r2] = 0.f;

  const char* pkc = (const char*)pack + (size_t)((d * 640 + nt0) * 1024) + l * 16;

  short8 wq[4][2];   // B ring, depth 3
  short8 aq[2][2];   // A ping-pong

  // prime B stages 0..2 (stage s: cb=s/5=0, t=s)
#pragma unroll
  for (int s = 0; s < 3; ++s) {
    const size_t bo = (size_t)(s * 16) * 8192;
    wq[s][0] = *(const short8*)(pkc + bo);
    wq[s][1] = *(const short8*)(pkc + bo + 4096);
  }
  // prime A for s=0 (t=0, cbl=0, hf=0)
  {
    const int off = P0[0] + hh5[0];
    aq[0][0] = *(const short8*)(lds + off);
    aq[0][1] = *(const short8*)(lds + off + 2 * SSTR);
  }

#define KSTAGE(S, HF)                                                          \
  {                                                                            \
    if ((S) + 3 < 80) {                                                        \
      const int s3 = (S) + 3, cb3 = s3 / 5, t3 = s3 - cb3 * 5;                 \
      const size_t bo = (size_t)(t3 * 16 + cb3) * 8192;                        \
      wq[s3 & 3][0] = *(const short8*)(pkc + bo);                              \
      wq[s3 & 3][1] = *(const short8*)(pkc + bo + 4096);                       \
    }                                                                          \
    if ((S) + 1 < ((HF) + 1) * 40) {                                           \
      const int s1 = (S) + 1, cbl1 = (s1 % 40) / 5, t1 = s1 % 5;               \
      const int off = (HF) * HSTR + P0[t1] + (((cbl1 << 5) ^ hh5[t1]));        \
      aq[s1 & 1][0] = *(const short8*)(lds + off);                             \
      aq[s1 & 1][1] = *(const short8*)(lds + off + 2 * SSTR);                  \
    }                                                                          \
    acc[0][0] = __builtin_amdgcn_mfma_f32_32x32x16_bf16(aq[(S)&1][0], wq[(S)&3][0], acc[0][0], 0, 0, 0); \
    acc[0][1] = __builtin_amdgcn_mfma_f32_32x32x16_bf16(aq[(S)&1][0], wq[(S)&3][1], acc[0][1], 0, 0, 0); \
    acc[1][0] = __builtin_amdgcn_mfma_f32_32x32x16_bf16(aq[(S)&1][1], wq[(S)&3][0], acc[1][0], 0, 0, 0); \
    acc[1][1] = __builtin_amdgcn_mfma_f32_32x32x16_bf16(aq[(S)&1][1], wq[(S)&3][1], acc[1][1], 0, 0, 0); \
  }

  // ---- chunk 0 (hf=0, stages 0..39) with hf=1 staging interleaved ----
#pragma unroll
  for (int g2 = 0; g2 < 8; ++g2) {
    int sj = 0, g16 = 0;
    bool valid = false;
    if (g2 < 6) {
      int job = g2 * 12 + w;
      if (job < 64) { valid = true; sj = job >> 4; g16 = job & 15; }
    }
    float f0, f1, f2, f3, f4, f5, f6, f7;
    if (valid) {
      const float* xs = xw + (size_t)sj * 16384 + (128 + g16 * 8) * 64;
      f0 = xs[0];   f1 = xs[64];  f2 = xs[128]; f3 = xs[192];
      f4 = xs[256]; f5 = xs[320]; f6 = xs[384]; f7 = xs[448];
    }
    KSTAGE(g2 * 5 + 0, 0)
    KSTAGE(g2 * 5 + 1, 0)
    KSTAGE(g2 * 5 + 2, 0)
    KSTAGE(g2 * 5 + 3, 0)
    KSTAGE(g2 * 5 + 4, 0)
    if (valid) {
      union { u16 u[8]; short8 v; } cv;
      cv.u[0] = f2bf(f0); cv.u[1] = f2bf(f1); cv.u[2] = f2bf(f2); cv.u[3] = f2bf(f3);
      cv.u[4] = f2bf(f4); cv.u[5] = f2bf(f5); cv.u[6] = f2bf(f6); cv.u[7] = f2bf(f7);
#pragma unroll
      for (int k2 = 0; k2 < 3; ++k2)
        if (whh[k2] >= 0)
          *(short8*)(lds + sj * SSTR + HSTR + wrow[k2] + ((g16 ^ whh[k2]) << 4)) = cv.v;
    }
  }
  __syncthreads();

  // prime A for s=40 (t=0, cbl=0, hf=1)
  {
    const int off = HSTR + P0[0] + hh5[0];
    aq[0][0] = *(const short8*)(lds + off);
    aq[0][1] = *(const short8*)(lds + off + 2 * SSTR);
  }

  // ---- chunk 1 (hf=1, stages 40..79), clean ----
#pragma unroll
  for (int g2 = 0; g2 < 8; ++g2) {
    KSTAGE(40 + g2 * 5 + 0, 1)
    KSTAGE(40 + g2 * 5 + 1, 1)
    KSTAGE(40 + g2 * 5 + 2, 1)
    KSTAGE(40 + g2 * 5 + 3, 1)
    KSTAGE(40 + g2 * 5 + 4, 1)
  }
  __syncthreads();

  // ---- epilogue: LDS out-tile (swizzled), bias + zero-mask ----
  const float* bp = (d == 0) ? bU : ((d == 1) ? bL : bR);
  const int ol = l & 31;
  const int o0 = nt0 * 32 + ol;
  const int o1 = o0 + 128;
  const float bias0 = bp[o0];
  const float bias1 = bp[o1];
  const int lh4 = lh * 4;
  float* ldsf = (float*)lds;

#pragma unroll
  for (int s4 = 0; s4 < 4; ++s4) {
    const int p  = s4 >> 1;
    const int hs = s4 & 1;
#pragma unroll
    for (int r2 = 0; r2 < 16; ++r2) {
      int row = (r2 & 3) + 8 * (r2 >> 2) + lh4;
      if ((row >> 4) == hs) {
        int p2 = row & 15;
        int i2 = p2 >> 2, j2 = p2 & 3;
        int outp = 16 * i2 + 2 * j2 + ((d > 0) ? 8 : 0) + (d >> 1);
        ldsf[o0 * 64 + (outp ^ ((o0 & 15) << 2))] = acc[p][0][r2] + bias0;
        ldsf[o1 * 64 + (outp ^ ((o1 & 15) << 2))] = acc[p][1][r2] + bias1;
      }
    }
    __syncthreads();
    for (int cc = tid; cc < 4096; cc += 768) {
      int o  = cc >> 4, pb = cc & 15;
      f32x4 v = *(f32x4*)(ldsf + o * 64 + ((pb ^ (o & 15)) << 2));
#pragma unroll
      for (int kk = 0; kk < 4; ++kk)
        if ((ZMASK >> (pb * 4 + kk)) & 1ull) v[kk] = 0.f;
      *(f32x4*)(out + (((size_t)(b0 + s4) * 256 + o) << 6) + pb * 4) = v;
    }
    __syncthreads();
  }
}

// ---------------- slow fp32 fallback (only if ws too small) -----------------
__global__ __launch_bounds__(256) void kag_fallback(const float* __restrict__ x,
    const float* __restrict__ wU, const float* __restrict__ bU,
    const float* __restrict__ wL, const float* __restrict__ bL,
    const float* __restrict__ wR, const float* __restrict__ bR,
    float* __restrict__ out) {
  long long tid = (long long)blockIdx.x * 256 + threadIdx.x;
  if (tid >= (long long)2048 * 256 * 48) return;
  int pd = (int)(tid % 48);
  long long rem = tid / 48;
  int o = (int)(rem % 256);
  int b = (int)(rem / 256);
  int d = pd >> 4, pos = pd & 15;
  int i = pos >> 2, j = pos & 3;
  int outp = 16 * i + 2 * j + ((d > 0) ? 8 : 0) + (d >> 1);
  if ((ZMASK >> outp) & 1ull) return;
  const float* ws = (d == 0) ? wU : ((d == 1) ? wL : wR);
  const float* bs = (d == 0) ? bU : ((d == 1) ? bL : bR);
  float acc = bs[o];
  int spv[5], wofs[5];
#pragma unroll
  for (int t = 0; t < 5; ++t) {
    int tr = TAPR[d][t], tc = TAPC[d][t];
    spv[t]  = (2 * i + tr) * 10 + (2 * j + tc);
    wofs[t] = tr * 4 + tc;
  }
  for (int c = 0; c < 256; ++c) {
    const float* xc = x + ((size_t)b * 256 + c) * 64;
    const float* wc = ws + (size_t)o * 4096 + (size_t)c * 16;
#pragma unroll
    for (int t = 0; t < 5; ++t) {
      int px = MAP100[spv[t]];
      if (px >= 0) acc += xc[px] * wc[wofs[t]];
    }
  }
  out[((size_t)b * 256 + o) * 64 + outp] = acc;
}

extern "C" void kernel_launch(void* const* d_in, const int* in_sizes, int n_in,
                              void* d_out, int out_size, void* d_ws, size_t ws_size,
                              hipStream_t stream) {
  const float* x  = (const float*)d_in[0];
  const float* wU = (const float*)d_in[1];
  const float* bU = (const float*)d_in[2];
  const float* wL = (const float*)d_in[3];
  const float* bL = (const float*)d_in[4];
  const float* wR = (const float*)d_in[5];
  const float* bR = (const float*)d_in[6];
  float* out = (float*)d_out;

  if (ws_size >= PACK_BYTES) {
    u16* pack = (u16*)d_ws;
    kag_prep<<<480, 256, 0, stream>>>(wU, wL, wR, pack);
    hipFuncSetAttribute(reinterpret_cast<const void*>(kag_main),
                        hipFuncAttributeMaxDynamicSharedMemorySize, LDSB);
    kag_main<<<512, 768, LDSB, stream>>>(x, pack, bU, bL, bR, out);
  } else {
    hipMemsetAsync(d_out, 0, (size_t)out_size * 4, stream);
    kag_fallback<<<98304, 256, 0, stream>>>(x, wU, bU, wL, bL, wR, bR, out);
  }
}